// Round 1
// baseline (1123.300 us; speedup 1.0000x reference)
//
#include <hip/hip_runtime.h>

#define NN 6144
#define F1 128

typedef __attribute__((ext_vector_type(8))) short short8_t;
typedef __attribute__((ext_vector_type(4))) float f32x4;

__device__ __forceinline__ unsigned short f2bf(float f) {
  unsigned int u = __float_as_uint(f);
  unsigned int r = (u + 0x7fffu + ((u >> 16) & 1u)) >> 16;
  return (unsigned short)r;
}

// ---------------------------------------------------------------- prep
// h = relu(x5 @ W_gat + b_gat)  (N,6) -> hT (6,N)
// sq[i] = sum(h_i^2)
// h2 = relu(x0 @ W_lin + b_lin) (N,128) -> Tx0 (f32 row-major), XT0 (bf16, transposed 128xN)
__global__ __launch_bounds__(128) void prep_kernel(
    const float* __restrict__ x5, const float* __restrict__ x0,
    const float* __restrict__ W_gat, const float* __restrict__ b_gat,
    const float* __restrict__ W_lin, const float* __restrict__ b_lin,
    float* __restrict__ hT, float* __restrict__ sq,
    float* __restrict__ Tx0, unsigned short* __restrict__ XT0) {
  int i = blockIdx.x;
  int t = threadIdx.x;
  __shared__ float xs[64];
  __shared__ float x5s[3];
  __shared__ float hs[6];
  if (t < 3) x5s[t] = x5[i * 3 + t];
  if (t < 64) xs[t] = x0[(size_t)i * 64 + t];
  __syncthreads();
  if (t < 6) {
    float a = b_gat[t];
#pragma unroll
    for (int k = 0; k < 3; k++) a += x5s[k] * W_gat[k * 6 + t];
    a = fmaxf(a, 0.f);
    hs[t] = a;
    hT[(size_t)t * NN + i] = a;
  }
  __syncthreads();
  if (t == 0) {
    float s = 0.f;
#pragma unroll
    for (int k = 0; k < 6; k++) s += hs[k] * hs[k];
    sq[i] = s;
  }
  float a = b_lin[t];
#pragma unroll 16
  for (int k = 0; k < 64; k++) a += xs[k] * W_lin[k * 128 + t];
  a = fmaxf(a, 0.f);
  Tx0[(size_t)i * F1 + t] = a;
  XT0[(size_t)t * NN + i] = f2bf(a);
}

// ---------------------------------------------------------------- prob
// P[i][j] = exp(-0.5*(sq_i + sq_j - 2 h_i.h_j)); deg_i = rowsum excl diag; dinv
__global__ __launch_bounds__(256) void prob_kernel(
    const float* __restrict__ hT, const float* __restrict__ sq,
    float* __restrict__ P, float* __restrict__ dinv) {
  int i = blockIdx.x;
  int t = threadIdx.x;
  float h0 = hT[i], h1 = hT[NN + i], h2 = hT[2 * NN + i];
  float h3 = hT[3 * NN + i], h4 = hT[4 * NN + i], h5 = hT[5 * NN + i];
  float si = sq[i];
  float acc = 0.f;
  float* Pr = P + (size_t)i * NN;
  for (int j = t; j < NN; j += 256) {
    float dot = h0 * hT[j] + h1 * hT[NN + j] + h2 * hT[2 * NN + j] +
                h3 * hT[3 * NN + j] + h4 * hT[4 * NN + j] + h5 * hT[5 * NN + j];
    float d = si + sq[j] - 2.f * dot;
    float p = __expf(-0.5f * d);
    Pr[j] = p;
    if (j != i) acc += p;
  }
  __shared__ float red[256];
  red[t] = acc;
  __syncthreads();
  for (int s = 128; s > 0; s >>= 1) {
    if (t < s) red[t] += red[t + s];
    __syncthreads();
  }
  if (t == 0) {
    float deg = red[0];
    dinv[i] = deg > 0.f ? rsqrtf(deg) : 0.f;
  }
}

// ---------------------------------------------------------------- smat
// S[i][j] = (i==j) ? 0 : -(dinv_i * P_ij * dinv_j), stored bf16
__global__ __launch_bounds__(256) void smat_kernel(
    const float* __restrict__ P, const float* __restrict__ dinv,
    unsigned short* __restrict__ Sb) {
  int i = blockIdx.x;
  float di = dinv[i];
  const float* Pr = P + (size_t)i * NN;
  unsigned short* Sr = Sb + (size_t)i * NN;
  for (int j = threadIdx.x; j < NN; j += 256) {
    float s = (j == i) ? 0.f : -(di * Pr[j] * dinv[j]);
    Sr[j] = f2bf(s);
  }
}

// ---------------------------------------------------------------- gemm (split-K partials)
// partial[ks] += S[ks-chunk] @ X   ; S: NxN bf16 row-major, XT: 128xN bf16 (transposed operand)
// grid (96, 8), block 256 (4 waves); wave computes 16 rows x 128 cols.
__global__ __launch_bounds__(256) void gemm_kernel(
    const unsigned short* __restrict__ S, const unsigned short* __restrict__ XT,
    float* __restrict__ partial) {
  const int KC = NN / 8;  // 768
  int mb = blockIdx.x;
  int ks = blockIdx.y;
  int w = threadIdx.x >> 6;
  int l = threadIdx.x & 63;
  int lr = l & 15;   // row-in-tile for A, col-in-tile for B/C
  int lg = l >> 4;   // k-group
  int row = mb * 64 + w * 16 + lr;
  int k0 = ks * KC;

  f32x4 acc[8];
#pragma unroll
  for (int n = 0; n < 8; n++) acc[n] = (f32x4){0.f, 0.f, 0.f, 0.f};

  const unsigned short* Ab = S + (size_t)row * NN + k0 + lg * 8;
  const unsigned short* Bb = XT + (size_t)lr * NN + k0 + lg * 8;

  for (int kk = 0; kk < KC; kk += 32) {
    short8_t a = *(const short8_t*)(Ab + kk);
#pragma unroll
    for (int n = 0; n < 8; n++) {
      short8_t b = *(const short8_t*)(Bb + (size_t)n * 16 * NN + kk);
      acc[n] = __builtin_amdgcn_mfma_f32_16x16x32_bf16(a, b, acc[n], 0, 0, 0);
    }
  }

  // C/D layout: col = lane&15, row = (lane>>4)*4 + reg
  float* pbase = partial + (size_t)ks * NN * F1;
  int rowo = mb * 64 + w * 16 + lg * 4;
#pragma unroll
  for (int n = 0; n < 8; n++) {
#pragma unroll
    for (int r = 0; r < 4; r++) {
      pbase[(size_t)(rowo + r) * F1 + n * 16 + lr] = acc[n][r];
    }
  }
}

// ---------------------------------------------------------------- finalize
// g = sum_s partial[s]; if dsub: g = 2g - Tx_{k-2}; write Tx_k (f32) and XT_k (bf16 transposed)
__global__ __launch_bounds__(256) void finalize_kernel(
    const float4* __restrict__ partial, const float4* __restrict__ prevprev,
    float4* __restrict__ TxOut, unsigned short* __restrict__ XTout, int dsub) {
  const int TOT = NN * F1 / 4;  // 196608
  int idx = blockIdx.x * 256 + threadIdx.x;
  float4 g = make_float4(0.f, 0.f, 0.f, 0.f);
#pragma unroll
  for (int s = 0; s < 8; s++) {
    float4 p = partial[(size_t)s * TOT + idx];
    g.x += p.x; g.y += p.y; g.z += p.z; g.w += p.w;
  }
  if (dsub) {
    float4 q = prevprev[idx];
    g.x = 2.f * g.x - q.x; g.y = 2.f * g.y - q.y;
    g.z = 2.f * g.z - q.z; g.w = 2.f * g.w - q.w;
  }
  TxOut[idx] = g;
  int f = idx << 2;
  int row = f >> 7;
  int col = f & 127;
  size_t b = (size_t)col * NN + row;
  XTout[b] = f2bf(g.x);
  XTout[b + NN] = f2bf(g.y);
  XTout[b + 2 * (size_t)NN] = f2bf(g.z);
  XTout[b + 3 * (size_t)NN] = f2bf(g.w);
}

// ---------------------------------------------------------------- epilogue
// o3/o6/o9 from Tx[0..8], last_out, softmax(last_out @ W_last + b_last)
__global__ __launch_bounds__(256) void out_kernel(
    const float* __restrict__ Tx,
    const float* __restrict__ W3, const float* __restrict__ b3,
    const float* __restrict__ W6, const float* __restrict__ b6,
    const float* __restrict__ W9, const float* __restrict__ b9,
    const float* __restrict__ Wl, const float* __restrict__ bl,
    float* __restrict__ x_out, float* __restrict__ last_out) {
  int c = threadIdx.x;   // 0..15
  int ty = threadIdx.y;  // 0..15
  int row = blockIdx.x * 16 + ty;
  float o3 = b3[c], o6 = b6[c], o9 = b9[c];
  for (int k = 0; k < 9; k++) {
    const float* txr = Tx + ((size_t)k * NN + row) * F1;
    const float* w9p = W9 + (size_t)k * F1 * 16 + c;
    const float* w6p = W6 + (size_t)k * F1 * 16 + c;
    const float* w3p = W3 + (size_t)k * F1 * 16 + c;
    for (int j = 0; j < F1; j++) {
      float tv = txr[j];
      o9 += tv * w9p[j * 16];
      if (k < 6) o6 += tv * w6p[j * 16];
      if (k < 3) o3 += tv * w3p[j * 16];
    }
  }
  size_t lb = (size_t)row * 48;
  last_out[lb + c] = o3;
  last_out[lb + 16 + c] = o6;
  last_out[lb + 32 + c] = o9;
  __shared__ float lo[16][48];
  __shared__ float lg[16][16];
  __shared__ float le[16][16];
  lo[ty][c] = o3; lo[ty][16 + c] = o6; lo[ty][32 + c] = o9;
  __syncthreads();
  float logit = bl[c];
#pragma unroll
  for (int j = 0; j < 48; j++) logit += lo[ty][j] * Wl[j * 16 + c];
  lg[ty][c] = logit;
  __syncthreads();
  float mx = lg[ty][0];
#pragma unroll
  for (int j = 1; j < 16; j++) mx = fmaxf(mx, lg[ty][j]);
  float e = __expf(logit - mx);
  le[ty][c] = e;
  __syncthreads();
  float sum = 0.f;
#pragma unroll
  for (int j = 0; j < 16; j++) sum += le[ty][j];
  x_out[(size_t)row * 16 + c] = e / sum;
}

// ---------------------------------------------------------------- misc copies
__global__ __launch_bounds__(256) void copy_kernel(
    const int* __restrict__ tr, const int* __restrict__ val,
    const float* __restrict__ x0, float* __restrict__ tr_out,
    float* __restrict__ val_out, float* __restrict__ x0_out) {
  int i = blockIdx.x * 256 + threadIdx.x;
  if (i < 4000) tr_out[i] = (float)tr[i];
  if (i < 1000) val_out[i] = (float)val[i];
  if (i < NN * 64) x0_out[i] = x0[i];
}

extern "C" void kernel_launch(void* const* d_in, const int* in_sizes, int n_in,
                              void* d_out, int out_size, void* d_ws, size_t ws_size,
                              hipStream_t stream) {
  const float* x5 = (const float*)d_in[0];
  const float* x0 = (const float*)d_in[1];
  const int* tr = (const int*)d_in[2];
  const int* val = (const int*)d_in[3];
  const float* W_gat = (const float*)d_in[4];
  const float* b_gat = (const float*)d_in[5];
  const float* W_lin = (const float*)d_in[6];
  const float* b_lin = (const float*)d_in[7];
  const float* W3 = (const float*)d_in[8];
  const float* b3 = (const float*)d_in[9];
  const float* W6 = (const float*)d_in[10];
  const float* b6 = (const float*)d_in[11];
  const float* W9 = (const float*)d_in[12];
  const float* b9 = (const float*)d_in[13];
  const float* Wl = (const float*)d_in[14];
  const float* bl = (const float*)d_in[15];

  float* out = (float*)d_out;
  float* x_out = out;
  float* tr_out = x_out + (size_t)NN * 16;
  float* val_out = tr_out + 4000;
  float* P = val_out + 1000;
  float* last_out = P + (size_t)NN * NN;
  float* x0_out = last_out + (size_t)NN * 48;

  char* w = (char*)d_ws;
  unsigned short* Sb = (unsigned short*)w;  w += (size_t)NN * NN * 2;
  float* Tx = (float*)w;                    w += (size_t)9 * NN * F1 * 4;
  float* partial = (float*)w;               w += (size_t)8 * NN * F1 * 4;
  unsigned short* XTa = (unsigned short*)w; w += (size_t)NN * F1 * 2;
  unsigned short* XTb = (unsigned short*)w; w += (size_t)NN * F1 * 2;
  float* hT = (float*)w;                    w += (size_t)6 * NN * 4;
  float* sq = (float*)w;                    w += (size_t)NN * 4;
  float* dinv = (float*)w;                  w += (size_t)NN * 4;

  prep_kernel<<<NN, 128, 0, stream>>>(x5, x0, W_gat, b_gat, W_lin, b_lin, hT, sq,
                                      Tx, XTa);
  prob_kernel<<<NN, 256, 0, stream>>>(hT, sq, P, dinv);
  smat_kernel<<<NN, 256, 0, stream>>>(P, dinv, Sb);

  unsigned short* xin = XTa;
  unsigned short* xout = XTb;
  for (int k = 1; k <= 8; k++) {
    gemm_kernel<<<dim3(96, 8), 256, 0, stream>>>(Sb, xin, partial);
    const float4* pp = (const float4*)(Tx + (size_t)(k >= 2 ? k - 2 : 0) * NN * F1);
    finalize_kernel<<<768, 256, 0, stream>>>((const float4*)partial, pp,
                                             (float4*)(Tx + (size_t)k * NN * F1),
                                             xout, k >= 2 ? 1 : 0);
    unsigned short* tmp = xin; xin = xout; xout = tmp;
  }

  out_kernel<<<dim3(NN / 16), dim3(16, 16), 0, stream>>>(
      Tx, W3, b3, W6, b6, W9, b9, Wl, bl, x_out, last_out);
  copy_kernel<<<1536, 256, 0, stream>>>(tr, val, x0, tr_out, val_out, x0_out);
}

// Round 2
// 841.964 us; speedup vs baseline: 1.3341x; 1.3341x over previous
//
#include <hip/hip_runtime.h>

#define NN 6144
#define F1 128

typedef __attribute__((ext_vector_type(8))) short short8_t;
typedef __attribute__((ext_vector_type(4))) float f32x4;

__device__ __forceinline__ unsigned short f2bf(float f) {
  unsigned int u = __float_as_uint(f);
  unsigned int r = (u + 0x7fffu + ((u >> 16) & 1u)) >> 16;
  return (unsigned short)r;
}

// ---------------------------------------------------------------- prep
__global__ __launch_bounds__(128) void prep_kernel(
    const float* __restrict__ x5, const float* __restrict__ x0,
    const float* __restrict__ W_gat, const float* __restrict__ b_gat,
    const float* __restrict__ W_lin, const float* __restrict__ b_lin,
    float* __restrict__ hT, float* __restrict__ sq,
    float* __restrict__ Tx0, unsigned short* __restrict__ XT0) {
  int i = blockIdx.x;
  int t = threadIdx.x;
  __shared__ float xs[64];
  __shared__ float x5s[3];
  __shared__ float hs[6];
  if (t < 3) x5s[t] = x5[i * 3 + t];
  if (t < 64) xs[t] = x0[(size_t)i * 64 + t];
  __syncthreads();
  if (t < 6) {
    float a = b_gat[t];
#pragma unroll
    for (int k = 0; k < 3; k++) a += x5s[k] * W_gat[k * 6 + t];
    a = fmaxf(a, 0.f);
    hs[t] = a;
    hT[(size_t)t * NN + i] = a;
  }
  __syncthreads();
  if (t == 0) {
    float s = 0.f;
#pragma unroll
    for (int k = 0; k < 6; k++) s += hs[k] * hs[k];
    sq[i] = s;
  }
  float a = b_lin[t];
#pragma unroll 16
  for (int k = 0; k < 64; k++) a += xs[k] * W_lin[k * 128 + t];
  a = fmaxf(a, 0.f);
  Tx0[(size_t)i * F1 + t] = a;
  XT0[(size_t)t * NN + i] = f2bf(a);
}

// ---------------------------------------------------------------- prob
// P[i][j] = exp(-0.5*(sq_i + sq_j - 2 h_i.h_j)); deg_i = rowsum excl diag
__global__ __launch_bounds__(256) void prob_kernel(
    const float* __restrict__ hT, const float* __restrict__ sq,
    float* __restrict__ P, float* __restrict__ dinv) {
  int i = blockIdx.x;
  int t = threadIdx.x;
  float h0 = hT[i], h1 = hT[NN + i], h2 = hT[2 * NN + i];
  float h3 = hT[3 * NN + i], h4 = hT[4 * NN + i], h5 = hT[5 * NN + i];
  float si = sq[i];
  float acc = 0.f;
  float* Pr = P + (size_t)i * NN;
  for (int j = t; j < NN; j += 256) {
    float dot = h0 * hT[j] + h1 * hT[NN + j] + h2 * hT[2 * NN + j] +
                h3 * hT[3 * NN + j] + h4 * hT[4 * NN + j] + h5 * hT[5 * NN + j];
    float d = si + sq[j] - 2.f * dot;
    float p = __expf(-0.5f * d);
    Pr[j] = p;
    if (j != i) acc += p;
  }
  __shared__ float red[256];
  red[t] = acc;
  __syncthreads();
  for (int s = 128; s > 0; s >>= 1) {
    if (t < s) red[t] += red[t + s];
    __syncthreads();
  }
  if (t == 0) {
    float deg = red[0];
    dinv[i] = deg > 0.f ? rsqrtf(deg) : 0.f;
  }
}

// ---------------------------------------------------------------- smat
// Recompute the gaussian (cheaper than re-reading 151MB of P):
// S[i][j] = (i==j) ? 0 : -(dinv_i * exp(-0.5*d_ij) * dinv_j), stored bf16
__global__ __launch_bounds__(256) void smat_kernel(
    const float* __restrict__ hT, const float* __restrict__ sq,
    const float* __restrict__ dinv, unsigned short* __restrict__ Sb) {
  int i = blockIdx.x;
  int t = threadIdx.x;
  float h0 = hT[i], h1 = hT[NN + i], h2 = hT[2 * NN + i];
  float h3 = hT[3 * NN + i], h4 = hT[4 * NN + i], h5 = hT[5 * NN + i];
  float si = sq[i];
  float di = dinv[i];
  unsigned short* Sr = Sb + (size_t)i * NN;
  for (int j = t; j < NN; j += 256) {
    float dot = h0 * hT[j] + h1 * hT[NN + j] + h2 * hT[2 * NN + j] +
                h3 * hT[3 * NN + j] + h4 * hT[4 * NN + j] + h5 * hT[5 * NN + j];
    float d = si + sq[j] - 2.f * dot;
    float p = __expf(-0.5f * d);
    float s = (j == i) ? 0.f : -(di * p * dinv[j]);
    Sr[j] = f2bf(s);
  }
}

// ---------------------------------------------------------------- gemm (split-K partials)
__global__ __launch_bounds__(256) void gemm_kernel(
    const unsigned short* __restrict__ S, const unsigned short* __restrict__ XT,
    float* __restrict__ partial) {
  const int KC = NN / 8;  // 768
  int mb = blockIdx.x;
  int ks = blockIdx.y;
  int w = threadIdx.x >> 6;
  int l = threadIdx.x & 63;
  int lr = l & 15;
  int lg = l >> 4;
  int row = mb * 64 + w * 16 + lr;
  int k0 = ks * KC;

  f32x4 acc[8];
#pragma unroll
  for (int n = 0; n < 8; n++) acc[n] = (f32x4){0.f, 0.f, 0.f, 0.f};

  const unsigned short* Ab = S + (size_t)row * NN + k0 + lg * 8;
  const unsigned short* Bb = XT + (size_t)lr * NN + k0 + lg * 8;

  for (int kk = 0; kk < KC; kk += 32) {
    short8_t a = *(const short8_t*)(Ab + kk);
#pragma unroll
    for (int n = 0; n < 8; n++) {
      short8_t b = *(const short8_t*)(Bb + (size_t)n * 16 * NN + kk);
      acc[n] = __builtin_amdgcn_mfma_f32_16x16x32_bf16(a, b, acc[n], 0, 0, 0);
    }
  }

  float* pbase = partial + (size_t)ks * NN * F1;
  int rowo = mb * 64 + w * 16 + lg * 4;
#pragma unroll
  for (int n = 0; n < 8; n++) {
#pragma unroll
    for (int r = 0; r < 4; r++) {
      pbase[(size_t)(rowo + r) * F1 + n * 16 + lr] = acc[n][r];
    }
  }
}

// ---------------------------------------------------------------- finalize
__global__ __launch_bounds__(256) void finalize_kernel(
    const float4* __restrict__ partial, const float4* __restrict__ prevprev,
    float4* __restrict__ TxOut, unsigned short* __restrict__ XTout, int dsub) {
  const int TOT = NN * F1 / 4;
  int idx = blockIdx.x * 256 + threadIdx.x;
  float4 g = make_float4(0.f, 0.f, 0.f, 0.f);
#pragma unroll
  for (int s = 0; s < 8; s++) {
    float4 p = partial[(size_t)s * TOT + idx];
    g.x += p.x; g.y += p.y; g.z += p.z; g.w += p.w;
  }
  if (dsub) {
    float4 q = prevprev[idx];
    g.x = 2.f * g.x - q.x; g.y = 2.f * g.y - q.y;
    g.z = 2.f * g.z - q.z; g.w = 2.f * g.w - q.w;
  }
  TxOut[idx] = g;
  int f = idx << 2;
  int row = f >> 7;
  int col = f & 127;
  size_t b = (size_t)col * NN + row;
  XTout[b] = f2bf(g.x);
  XTout[b + NN] = f2bf(g.y);
  XTout[b + 2 * (size_t)NN] = f2bf(g.z);
  XTout[b + 3 * (size_t)NN] = f2bf(g.w);
}

// ---------------------------------------------------------------- Wcat build
// Wcat[k][j][c]: c<16 -> W3[k] (k<3), c<32 -> W6[k] (k<6), else W9[k]; 0 elsewhere
__global__ __launch_bounds__(256) void wcat_kernel(
    const float* __restrict__ W3, const float* __restrict__ W6,
    const float* __restrict__ W9, float* __restrict__ Wcat) {
  int idx = blockIdx.x * 256 + threadIdx.x;
  if (idx >= 9 * 128 * 48) return;
  int c = idx % 48;
  int j = (idx / 48) % 128;
  int k = idx / (48 * 128);
  float v = 0.f;
  if (c < 16) {
    if (k < 3) v = W3[(k * 128 + j) * 16 + c];
  } else if (c < 32) {
    if (k < 6) v = W6[(k * 128 + j) * 16 + (c - 16)];
  } else {
    v = W9[(k * 128 + j) * 16 + (c - 32)];
  }
  Wcat[idx] = v;
}

// ---------------------------------------------------------------- epilogue
// 192 blocks x 256 threads; block owns 32 rows. LDS-tiled: per k stage
// Wcat[k] (24KB) + 32 Tx rows (padded), 2x3 register micro-tile per thread.
// Then fused last_out write + logits + softmax.
__global__ __launch_bounds__(256) void out_kernel(
    const float* __restrict__ Tx, const float* __restrict__ Wcat,
    const float* __restrict__ b3, const float* __restrict__ b6,
    const float* __restrict__ b9,
    const float* __restrict__ Wl, const float* __restrict__ bl,
    float* __restrict__ x_out, float* __restrict__ last_out) {
  __shared__ float WS[128 * 48];
  __shared__ float TxS[32][129];
  __shared__ float lo[32][48];
  __shared__ float lg[32][16];
  __shared__ float le[32][16];
  __shared__ float WlS[48 * 16];
  __shared__ float blS[16];
  int t = threadIdx.x;
  int row0 = blockIdx.x * 32;
  int rg = t >> 4;   // 0..15 -> rows {2rg, 2rg+1}
  int cg = t & 15;   // 0..15 -> cols {3cg..3cg+2}
  float acc[2][3] = {{0.f, 0.f, 0.f}, {0.f, 0.f, 0.f}};
  for (int i = t; i < 768; i += 256) WlS[i] = Wl[i];
  if (t < 16) blS[t] = bl[t];
  for (int k = 0; k < 9; k++) {
    for (int i = t; i < 6144; i += 256) WS[i] = Wcat[k * 6144 + i];
    for (int i = t; i < 4096; i += 256) {
      int r = i >> 7, j = i & 127;
      TxS[r][j] = Tx[((size_t)k * NN + row0 + r) * F1 + j];
    }
    __syncthreads();
#pragma unroll 4
    for (int j = 0; j < 128; j++) {
      float t0 = TxS[2 * rg][j], t1 = TxS[2 * rg + 1][j];
      const float* wp = &WS[j * 48 + 3 * cg];
      float w0 = wp[0], w1 = wp[1], w2 = wp[2];
      acc[0][0] += t0 * w0; acc[0][1] += t0 * w1; acc[0][2] += t0 * w2;
      acc[1][0] += t1 * w0; acc[1][1] += t1 * w1; acc[1][2] += t1 * w2;
    }
    __syncthreads();
  }
#pragma unroll
  for (int rr = 0; rr < 2; rr++) {
    int r = 2 * rg + rr;
#pragma unroll
    for (int cc = 0; cc < 3; cc++) {
      int c = 3 * cg + cc;
      float bias = c < 16 ? b3[c] : (c < 32 ? b6[c - 16] : b9[c - 32]);
      float v = acc[rr][cc] + bias;
      lo[r][c] = v;
      last_out[(size_t)(row0 + r) * 48 + c] = v;
    }
  }
  __syncthreads();
#pragma unroll
  for (int s = 0; s < 2; s++) {
    int idx = t + 256 * s;
    int r = idx >> 4, c = idx & 15;
    float lgt = blS[c];
#pragma unroll 8
    for (int j = 0; j < 48; j++) lgt += lo[r][j] * WlS[j * 16 + c];
    lg[r][c] = lgt;
  }
  __syncthreads();
#pragma unroll
  for (int s = 0; s < 2; s++) {
    int idx = t + 256 * s;
    int r = idx >> 4, c = idx & 15;
    float mx = lg[r][0];
#pragma unroll
    for (int j = 1; j < 16; j++) mx = fmaxf(mx, lg[r][j]);
    le[r][c] = __expf(lg[r][c] - mx);
  }
  __syncthreads();
#pragma unroll
  for (int s = 0; s < 2; s++) {
    int idx = t + 256 * s;
    int r = idx >> 4, c = idx & 15;
    float sum = 0.f;
#pragma unroll
    for (int j = 0; j < 16; j++) sum += le[r][j];
    x_out[(size_t)(row0 + r) * 16 + c] = le[r][c] / sum;
  }
}

// ---------------------------------------------------------------- misc copies
__global__ __launch_bounds__(256) void copy_kernel(
    const int* __restrict__ tr, const int* __restrict__ val,
    const float* __restrict__ x0, float* __restrict__ tr_out,
    float* __restrict__ val_out, float* __restrict__ x0_out) {
  int i = blockIdx.x * 256 + threadIdx.x;
  if (i < 4000) tr_out[i] = (float)tr[i];
  if (i < 1000) val_out[i] = (float)val[i];
  if (i < NN * 64) x0_out[i] = x0[i];
}

extern "C" void kernel_launch(void* const* d_in, const int* in_sizes, int n_in,
                              void* d_out, int out_size, void* d_ws, size_t ws_size,
                              hipStream_t stream) {
  const float* x5 = (const float*)d_in[0];
  const float* x0 = (const float*)d_in[1];
  const int* tr = (const int*)d_in[2];
  const int* val = (const int*)d_in[3];
  const float* W_gat = (const float*)d_in[4];
  const float* b_gat = (const float*)d_in[5];
  const float* W_lin = (const float*)d_in[6];
  const float* b_lin = (const float*)d_in[7];
  const float* W3 = (const float*)d_in[8];
  const float* b3 = (const float*)d_in[9];
  const float* W6 = (const float*)d_in[10];
  const float* b6 = (const float*)d_in[11];
  const float* W9 = (const float*)d_in[12];
  const float* b9 = (const float*)d_in[13];
  const float* Wl = (const float*)d_in[14];
  const float* bl = (const float*)d_in[15];

  float* out = (float*)d_out;
  float* x_out = out;
  float* tr_out = x_out + (size_t)NN * 16;
  float* val_out = tr_out + 4000;
  float* P = val_out + 1000;
  float* last_out = P + (size_t)NN * NN;
  float* x0_out = last_out + (size_t)NN * 48;

  char* w = (char*)d_ws;
  unsigned short* Sb = (unsigned short*)w;  w += (size_t)NN * NN * 2;
  float* Tx = (float*)w;                    w += (size_t)9 * NN * F1 * 4;
  float* partial = (float*)w;               w += (size_t)8 * NN * F1 * 4;
  unsigned short* XTa = (unsigned short*)w; w += (size_t)NN * F1 * 2;
  unsigned short* XTb = (unsigned short*)w; w += (size_t)NN * F1 * 2;
  float* hT = (float*)w;                    w += (size_t)6 * NN * 4;
  float* sq = (float*)w;                    w += (size_t)NN * 4;
  float* dinv = (float*)w;                  w += (size_t)NN * 4;
  float* Wcat = (float*)w;                  w += (size_t)9 * 128 * 48 * 4;

  prep_kernel<<<NN, 128, 0, stream>>>(x5, x0, W_gat, b_gat, W_lin, b_lin, hT, sq,
                                      Tx, XTa);
  prob_kernel<<<NN, 256, 0, stream>>>(hT, sq, P, dinv);
  smat_kernel<<<NN, 256, 0, stream>>>(hT, sq, dinv, Sb);
  wcat_kernel<<<216, 256, 0, stream>>>(W3, W6, W9, Wcat);

  unsigned short* xin = XTa;
  unsigned short* xout = XTb;
  for (int k = 1; k <= 8; k++) {
    gemm_kernel<<<dim3(96, 8), 256, 0, stream>>>(Sb, xin, partial);
    const float4* pp = (const float4*)(Tx + (size_t)(k >= 2 ? k - 2 : 0) * NN * F1);
    finalize_kernel<<<768, 256, 0, stream>>>((const float4*)partial, pp,
                                             (float4*)(Tx + (size_t)k * NN * F1),
                                             xout, k >= 2 ? 1 : 0);
    unsigned short* tmp = xin; xin = xout; xout = tmp;
  }

  out_kernel<<<192, 256, 0, stream>>>(Tx, Wcat, b3, b6, b9, Wl, bl, x_out,
                                      last_out);
  copy_kernel<<<1536, 256, 0, stream>>>(tr, val, x0, tr_out, val_out, x0_out);
}

// Round 3
// 618.471 us; speedup vs baseline: 1.8163x; 1.3614x over previous
//
#include <hip/hip_runtime.h>

#define NN 6144
#define F1 128
#define KSPLIT 6
#define KC 1024

typedef __attribute__((ext_vector_type(8))) short short8_t;
typedef __attribute__((ext_vector_type(4))) float f32x4;

__device__ __forceinline__ unsigned short f2bf(float f) {
  unsigned int u = __float_as_uint(f);
  unsigned int r = (u + 0x7fffu + ((u >> 16) & 1u)) >> 16;
  return (unsigned short)r;
}

// ---------------------------------------------------------------- prep
__global__ __launch_bounds__(128) void prep_kernel(
    const float* __restrict__ x5, const float* __restrict__ x0,
    const float* __restrict__ W_gat, const float* __restrict__ b_gat,
    const float* __restrict__ W_lin, const float* __restrict__ b_lin,
    float* __restrict__ hT, float* __restrict__ sq,
    float* __restrict__ Tx0, unsigned short* __restrict__ XT0) {
  int i = blockIdx.x;
  int t = threadIdx.x;
  __shared__ float xs[64];
  __shared__ float x5s[3];
  __shared__ float hs[6];
  if (t < 3) x5s[t] = x5[i * 3 + t];
  if (t < 64) xs[t] = x0[(size_t)i * 64 + t];
  __syncthreads();
  if (t < 6) {
    float a = b_gat[t];
#pragma unroll
    for (int k = 0; k < 3; k++) a += x5s[k] * W_gat[k * 6 + t];
    a = fmaxf(a, 0.f);
    hs[t] = a;
    hT[(size_t)t * NN + i] = a;
  }
  __syncthreads();
  if (t == 0) {
    float s = 0.f;
#pragma unroll
    for (int k = 0; k < 6; k++) s += hs[k] * hs[k];
    sq[i] = s;
  }
  float a = b_lin[t];
#pragma unroll 16
  for (int k = 0; k < 64; k++) a += xs[k] * W_lin[k * 128 + t];
  a = fmaxf(a, 0.f);
  Tx0[(size_t)i * F1 + t] = a;
  XT0[(size_t)t * NN + i] = f2bf(a);
}

// ---------------------------------------------------------------- prob
__global__ __launch_bounds__(256) void prob_kernel(
    const float* __restrict__ hT, const float* __restrict__ sq,
    float* __restrict__ P, float* __restrict__ dinv) {
  int i = blockIdx.x;
  int t = threadIdx.x;
  float h0 = hT[i], h1 = hT[NN + i], h2 = hT[2 * NN + i];
  float h3 = hT[3 * NN + i], h4 = hT[4 * NN + i], h5 = hT[5 * NN + i];
  float si = sq[i];
  float acc = 0.f;
  float* Pr = P + (size_t)i * NN;
  for (int j = t; j < NN; j += 256) {
    float dot = h0 * hT[j] + h1 * hT[NN + j] + h2 * hT[2 * NN + j] +
                h3 * hT[3 * NN + j] + h4 * hT[4 * NN + j] + h5 * hT[5 * NN + j];
    float d = si + sq[j] - 2.f * dot;
    float p = __expf(-0.5f * d);
    Pr[j] = p;
    if (j != i) acc += p;
  }
  __shared__ float red[256];
  red[t] = acc;
  __syncthreads();
  for (int s = 128; s > 0; s >>= 1) {
    if (t < s) red[t] += red[t + s];
    __syncthreads();
  }
  if (t == 0) {
    float deg = red[0];
    dinv[i] = deg > 0.f ? rsqrtf(deg) : 0.f;
  }
}

// ---------------------------------------------------------------- smat
__global__ __launch_bounds__(256) void smat_kernel(
    const float* __restrict__ hT, const float* __restrict__ sq,
    const float* __restrict__ dinv, unsigned short* __restrict__ Sb) {
  int i = blockIdx.x;
  int t = threadIdx.x;
  float h0 = hT[i], h1 = hT[NN + i], h2 = hT[2 * NN + i];
  float h3 = hT[3 * NN + i], h4 = hT[4 * NN + i], h5 = hT[5 * NN + i];
  float si = sq[i];
  float di = dinv[i];
  unsigned short* Sr = Sb + (size_t)i * NN;
  for (int j = t; j < NN; j += 256) {
    float dot = h0 * hT[j] + h1 * hT[NN + j] + h2 * hT[2 * NN + j] +
                h3 * hT[3 * NN + j] + h4 * hT[4 * NN + j] + h5 * hT[5 * NN + j];
    float d = si + sq[j] - 2.f * dot;
    float p = __expf(-0.5f * d);
    float s = (j == i) ? 0.f : -(di * p * dinv[j]);
    Sr[j] = f2bf(s);
  }
}

// ---------------------------------------------------------------- gemm (split-K partials)
// grid (48, KSPLIT), block 128 (2 waves); wave = 64 rows x 128 cols, KC k-chunk.
// 375 B of operand traffic per MFMA (A reuse x8, B reuse x4).
__global__ __launch_bounds__(128) void gemm_kernel(
    const unsigned short* __restrict__ S, const unsigned short* __restrict__ XT,
    float* __restrict__ partial) {
  // XCD-aware swizzle: 288 blocks = 8 XCDs x 36; same-ks blocks land together
  int lin = blockIdx.x + 48 * blockIdx.y;
  int swz = (lin & 7) * 36 + (lin >> 3);
  int mb = swz % 48;
  int ks = swz / 48;
  int w = threadIdx.x >> 6;
  int l = threadIdx.x & 63;
  int lr = l & 15;
  int lg = l >> 4;
  int row0 = mb * 128 + w * 64;
  int k0 = ks * KC;

  f32x4 acc[4][8];
#pragma unroll
  for (int rb = 0; rb < 4; rb++)
#pragma unroll
    for (int n = 0; n < 8; n++) acc[rb][n] = (f32x4){0.f, 0.f, 0.f, 0.f};

  const unsigned short* Ab = S + (size_t)(row0 + lr) * NN + k0 + lg * 8;
  const unsigned short* Bb = XT + (size_t)lr * NN + k0 + lg * 8;

#pragma unroll 2
  for (int kk = 0; kk < KC; kk += 32) {
    short8_t a0 = *(const short8_t*)(Ab + kk);
    short8_t a1 = *(const short8_t*)(Ab + (size_t)16 * NN + kk);
    short8_t a2 = *(const short8_t*)(Ab + (size_t)32 * NN + kk);
    short8_t a3 = *(const short8_t*)(Ab + (size_t)48 * NN + kk);
#pragma unroll
    for (int n = 0; n < 8; n++) {
      short8_t b = *(const short8_t*)(Bb + (size_t)n * 16 * NN + kk);
      acc[0][n] = __builtin_amdgcn_mfma_f32_16x16x32_bf16(a0, b, acc[0][n], 0, 0, 0);
      acc[1][n] = __builtin_amdgcn_mfma_f32_16x16x32_bf16(a1, b, acc[1][n], 0, 0, 0);
      acc[2][n] = __builtin_amdgcn_mfma_f32_16x16x32_bf16(a2, b, acc[2][n], 0, 0, 0);
      acc[3][n] = __builtin_amdgcn_mfma_f32_16x16x32_bf16(a3, b, acc[3][n], 0, 0, 0);
    }
  }

  // C/D layout: col = lane&15, row-in-16 = lg*4 + r
  float* pbase = partial + (size_t)ks * NN * F1;
#pragma unroll
  for (int rb = 0; rb < 4; rb++) {
    int rowo = row0 + rb * 16 + lg * 4;
#pragma unroll
    for (int n = 0; n < 8; n++) {
#pragma unroll
      for (int r = 0; r < 4; r++) {
        pbase[(size_t)(rowo + r) * F1 + n * 16 + lr] = acc[rb][n][r];
      }
    }
  }
}

// ---------------------------------------------------------------- finalize
__global__ __launch_bounds__(256) void finalize_kernel(
    const float4* __restrict__ partial, const float4* __restrict__ prevprev,
    float4* __restrict__ TxOut, unsigned short* __restrict__ XTout, int dsub) {
  const int TOT = NN * F1 / 4;
  int idx = blockIdx.x * 256 + threadIdx.x;
  float4 g = make_float4(0.f, 0.f, 0.f, 0.f);
#pragma unroll
  for (int s = 0; s < KSPLIT; s++) {
    float4 p = partial[(size_t)s * TOT + idx];
    g.x += p.x; g.y += p.y; g.z += p.z; g.w += p.w;
  }
  if (dsub) {
    float4 q = prevprev[idx];
    g.x = 2.f * g.x - q.x; g.y = 2.f * g.y - q.y;
    g.z = 2.f * g.z - q.z; g.w = 2.f * g.w - q.w;
  }
  TxOut[idx] = g;
  int f = idx << 2;
  int row = f >> 7;
  int col = f & 127;
  size_t b = (size_t)col * NN + row;
  XTout[b] = f2bf(g.x);
  XTout[b + NN] = f2bf(g.y);
  XTout[b + 2 * (size_t)NN] = f2bf(g.z);
  XTout[b + 3 * (size_t)NN] = f2bf(g.w);
}

// ---------------------------------------------------------------- Wcat build
__global__ __launch_bounds__(256) void wcat_kernel(
    const float* __restrict__ W3, const float* __restrict__ W6,
    const float* __restrict__ W9, float* __restrict__ Wcat) {
  int idx = blockIdx.x * 256 + threadIdx.x;
  if (idx >= 9 * 128 * 48) return;
  int c = idx % 48;
  int j = (idx / 48) % 128;
  int k = idx / (48 * 128);
  float v = 0.f;
  if (c < 16) {
    if (k < 3) v = W3[(k * 128 + j) * 16 + c];
  } else if (c < 32) {
    if (k < 6) v = W6[(k * 128 + j) * 16 + (c - 16)];
  } else {
    v = W9[(k * 128 + j) * 16 + (c - 32)];
  }
  Wcat[idx] = v;
}

// ---------------------------------------------------------------- epilogue
__global__ __launch_bounds__(256) void out_kernel(
    const float* __restrict__ Tx, const float* __restrict__ Wcat,
    const float* __restrict__ b3, const float* __restrict__ b6,
    const float* __restrict__ b9,
    const float* __restrict__ Wl, const float* __restrict__ bl,
    float* __restrict__ x_out, float* __restrict__ last_out) {
  __shared__ float WS[128 * 48];
  __shared__ float TxS[32][129];
  __shared__ float lo[32][48];
  __shared__ float lg[32][16];
  __shared__ float le[32][16];
  __shared__ float WlS[48 * 16];
  __shared__ float blS[16];
  int t = threadIdx.x;
  int row0 = blockIdx.x * 32;
  int rg = t >> 4;
  int cg = t & 15;
  float acc[2][3] = {{0.f, 0.f, 0.f}, {0.f, 0.f, 0.f}};
  for (int i = t; i < 768; i += 256) WlS[i] = Wl[i];
  if (t < 16) blS[t] = bl[t];
  for (int k = 0; k < 9; k++) {
    for (int i = t; i < 6144; i += 256) WS[i] = Wcat[k * 6144 + i];
    for (int i = t; i < 4096; i += 256) {
      int r = i >> 7, j = i & 127;
      TxS[r][j] = Tx[((size_t)k * NN + row0 + r) * F1 + j];
    }
    __syncthreads();
#pragma unroll 4
    for (int j = 0; j < 128; j++) {
      float t0 = TxS[2 * rg][j], t1 = TxS[2 * rg + 1][j];
      const float* wp = &WS[j * 48 + 3 * cg];
      float w0 = wp[0], w1 = wp[1], w2 = wp[2];
      acc[0][0] += t0 * w0; acc[0][1] += t0 * w1; acc[0][2] += t0 * w2;
      acc[1][0] += t1 * w0; acc[1][1] += t1 * w1; acc[1][2] += t1 * w2;
    }
    __syncthreads();
  }
#pragma unroll
  for (int rr = 0; rr < 2; rr++) {
    int r = 2 * rg + rr;
#pragma unroll
    for (int cc = 0; cc < 3; cc++) {
      int c = 3 * cg + cc;
      float bias = c < 16 ? b3[c] : (c < 32 ? b6[c - 16] : b9[c - 32]);
      float v = acc[rr][cc] + bias;
      lo[r][c] = v;
      last_out[(size_t)(row0 + r) * 48 + c] = v;
    }
  }
  __syncthreads();
#pragma unroll
  for (int s = 0; s < 2; s++) {
    int idx = t + 256 * s;
    int r = idx >> 4, c = idx & 15;
    float lgt = blS[c];
#pragma unroll 8
    for (int j = 0; j < 48; j++) lgt += lo[r][j] * WlS[j * 16 + c];
    lg[r][c] = lgt;
  }
  __syncthreads();
#pragma unroll
  for (int s = 0; s < 2; s++) {
    int idx = t + 256 * s;
    int r = idx >> 4, c = idx & 15;
    float mx = lg[r][0];
#pragma unroll
    for (int j = 1; j < 16; j++) mx = fmaxf(mx, lg[r][j]);
    le[r][c] = __expf(lg[r][c] - mx);
  }
  __syncthreads();
#pragma unroll
  for (int s = 0; s < 2; s++) {
    int idx = t + 256 * s;
    int r = idx >> 4, c = idx & 15;
    float sum = 0.f;
#pragma unroll
    for (int j = 0; j < 16; j++) sum += le[r][j];
    x_out[(size_t)(row0 + r) * 16 + c] = le[r][c] / sum;
  }
}

// ---------------------------------------------------------------- misc copies
__global__ __launch_bounds__(256) void copy_kernel(
    const int* __restrict__ tr, const int* __restrict__ val,
    const float* __restrict__ x0, float* __restrict__ tr_out,
    float* __restrict__ val_out, float* __restrict__ x0_out) {
  int i = blockIdx.x * 256 + threadIdx.x;
  if (i < 4000) tr_out[i] = (float)tr[i];
  if (i < 1000) val_out[i] = (float)val[i];
  if (i < NN * 64) x0_out[i] = x0[i];
}

extern "C" void kernel_launch(void* const* d_in, const int* in_sizes, int n_in,
                              void* d_out, int out_size, void* d_ws, size_t ws_size,
                              hipStream_t stream) {
  const float* x5 = (const float*)d_in[0];
  const float* x0 = (const float*)d_in[1];
  const int* tr = (const int*)d_in[2];
  const int* val = (const int*)d_in[3];
  const float* W_gat = (const float*)d_in[4];
  const float* b_gat = (const float*)d_in[5];
  const float* W_lin = (const float*)d_in[6];
  const float* b_lin = (const float*)d_in[7];
  const float* W3 = (const float*)d_in[8];
  const float* b3 = (const float*)d_in[9];
  const float* W6 = (const float*)d_in[10];
  const float* b6 = (const float*)d_in[11];
  const float* W9 = (const float*)d_in[12];
  const float* b9 = (const float*)d_in[13];
  const float* Wl = (const float*)d_in[14];
  const float* bl = (const float*)d_in[15];

  float* out = (float*)d_out;
  float* x_out = out;
  float* tr_out = x_out + (size_t)NN * 16;
  float* val_out = tr_out + 4000;
  float* P = val_out + 1000;
  float* last_out = P + (size_t)NN * NN;
  float* x0_out = last_out + (size_t)NN * 48;

  char* w = (char*)d_ws;
  unsigned short* Sb = (unsigned short*)w;  w += (size_t)NN * NN * 2;
  float* Tx = (float*)w;                    w += (size_t)9 * NN * F1 * 4;
  float* partial = (float*)w;               w += (size_t)KSPLIT * NN * F1 * 4;
  unsigned short* XTa = (unsigned short*)w; w += (size_t)NN * F1 * 2;
  unsigned short* XTb = (unsigned short*)w; w += (size_t)NN * F1 * 2;
  float* hT = (float*)w;                    w += (size_t)6 * NN * 4;
  float* sq = (float*)w;                    w += (size_t)NN * 4;
  float* dinv = (float*)w;                  w += (size_t)NN * 4;
  float* Wcat = (float*)w;                  w += (size_t)9 * 128 * 48 * 4;

  prep_kernel<<<NN, 128, 0, stream>>>(x5, x0, W_gat, b_gat, W_lin, b_lin, hT, sq,
                                      Tx, XTa);
  prob_kernel<<<NN, 256, 0, stream>>>(hT, sq, P, dinv);
  smat_kernel<<<NN, 256, 0, stream>>>(hT, sq, dinv, Sb);
  wcat_kernel<<<216, 256, 0, stream>>>(W3, W6, W9, Wcat);

  unsigned short* xin = XTa;
  unsigned short* xout = XTb;
  for (int k = 1; k <= 8; k++) {
    gemm_kernel<<<dim3(48, KSPLIT), 128, 0, stream>>>(Sb, xin, partial);
    const float4* pp = (const float4*)(Tx + (size_t)(k >= 2 ? k - 2 : 0) * NN * F1);
    finalize_kernel<<<768, 256, 0, stream>>>((const float4*)partial, pp,
                                             (float4*)(Tx + (size_t)k * NN * F1),
                                             xout, k >= 2 ? 1 : 0);
    unsigned short* tmp = xin; xin = xout; xout = tmp;
  }

  out_kernel<<<192, 256, 0, stream>>>(Tx, Wcat, b3, b6, b9, Wl, bl, x_out,
                                      last_out);
  copy_kernel<<<1536, 256, 0, stream>>>(tr, val, x0, tr_out, val_out, x0_out);
}

// Round 4
// 614.775 us; speedup vs baseline: 1.8272x; 1.0060x over previous
//
#include <hip/hip_runtime.h>

#define NN 6144
#define F1 128
#define KSPLIT 24
#define KC 256

typedef __attribute__((ext_vector_type(8))) short short8_t;
typedef __attribute__((ext_vector_type(4))) float f32x4;

__device__ __forceinline__ unsigned short f2bf(float f) {
  unsigned int u = __float_as_uint(f);
  unsigned int r = (u + 0x7fffu + ((u >> 16) & 1u)) >> 16;
  return (unsigned short)r;
}

// ---------------------------------------------------------------- prep
__global__ __launch_bounds__(128) void prep_kernel(
    const float* __restrict__ x5, const float* __restrict__ x0,
    const float* __restrict__ W_gat, const float* __restrict__ b_gat,
    const float* __restrict__ W_lin, const float* __restrict__ b_lin,
    float* __restrict__ hT, float* __restrict__ sq,
    float* __restrict__ Tx0, unsigned short* __restrict__ XT0) {
  int i = blockIdx.x;
  int t = threadIdx.x;
  __shared__ float xs[64];
  __shared__ float x5s[3];
  __shared__ float hs[6];
  if (t < 3) x5s[t] = x5[i * 3 + t];
  if (t < 64) xs[t] = x0[(size_t)i * 64 + t];
  __syncthreads();
  if (t < 6) {
    float a = b_gat[t];
#pragma unroll
    for (int k = 0; k < 3; k++) a += x5s[k] * W_gat[k * 6 + t];
    a = fmaxf(a, 0.f);
    hs[t] = a;
    hT[(size_t)t * NN + i] = a;
  }
  __syncthreads();
  if (t == 0) {
    float s = 0.f;
#pragma unroll
    for (int k = 0; k < 6; k++) s += hs[k] * hs[k];
    sq[i] = s;
  }
  float a = b_lin[t];
#pragma unroll 16
  for (int k = 0; k < 64; k++) a += xs[k] * W_lin[k * 128 + t];
  a = fmaxf(a, 0.f);
  Tx0[(size_t)i * F1 + t] = a;
  XT0[(size_t)t * NN + i] = f2bf(a);
}

// ---------------------------------------------------------------- prob
__global__ __launch_bounds__(256) void prob_kernel(
    const float* __restrict__ hT, const float* __restrict__ sq,
    float* __restrict__ P, float* __restrict__ dinv) {
  int i = blockIdx.x;
  int t = threadIdx.x;
  float h0 = hT[i], h1 = hT[NN + i], h2 = hT[2 * NN + i];
  float h3 = hT[3 * NN + i], h4 = hT[4 * NN + i], h5 = hT[5 * NN + i];
  float si = sq[i];
  float acc = 0.f;
  float* Pr = P + (size_t)i * NN;
  for (int j = t; j < NN; j += 256) {
    float dot = h0 * hT[j] + h1 * hT[NN + j] + h2 * hT[2 * NN + j] +
                h3 * hT[3 * NN + j] + h4 * hT[4 * NN + j] + h5 * hT[5 * NN + j];
    float d = si + sq[j] - 2.f * dot;
    float p = __expf(-0.5f * d);
    Pr[j] = p;
    if (j != i) acc += p;
  }
  __shared__ float red[256];
  red[t] = acc;
  __syncthreads();
  for (int s = 128; s > 0; s >>= 1) {
    if (t < s) red[t] += red[t + s];
    __syncthreads();
  }
  if (t == 0) {
    float deg = red[0];
    dinv[i] = deg > 0.f ? rsqrtf(deg) : 0.f;
  }
}

// ---------------------------------------------------------------- smat
__global__ __launch_bounds__(256) void smat_kernel(
    const float* __restrict__ hT, const float* __restrict__ sq,
    const float* __restrict__ dinv, unsigned short* __restrict__ Sb) {
  int i = blockIdx.x;
  int t = threadIdx.x;
  float h0 = hT[i], h1 = hT[NN + i], h2 = hT[2 * NN + i];
  float h3 = hT[3 * NN + i], h4 = hT[4 * NN + i], h5 = hT[5 * NN + i];
  float si = sq[i];
  float di = dinv[i];
  unsigned short* Sr = Sb + (size_t)i * NN;
  for (int j = t; j < NN; j += 256) {
    float dot = h0 * hT[j] + h1 * hT[NN + j] + h2 * hT[2 * NN + j] +
                h3 * hT[3 * NN + j] + h4 * hT[4 * NN + j] + h5 * hT[5 * NN + j];
    float d = si + sq[j] - 2.f * dot;
    float p = __expf(-0.5f * d);
    float s = (j == i) ? 0.f : -(di * p * dinv[j]);
    Sr[j] = f2bf(s);
  }
}

// ---------------------------------------------------------------- gemm (split-K partials)
// grid 1152 blocks x 128 thr (2 waves); wave = 64 rows x 128 cols, KC=256 k-chunk.
// 2304 waves = 2.25/SIMD (VGPR-capped residency 2/SIMD) -> latency hidden by TLP.
__global__ __launch_bounds__(128) void gemm_kernel(
    const unsigned short* __restrict__ S, const unsigned short* __restrict__ XT,
    float* __restrict__ partial) {
  // bijective XCD swizzle: 1152 = 8 XCDs x 144; same-ks blocks share B slice in L2
  int orig = blockIdx.x;
  int wgid = (orig & 7) * 144 + (orig >> 3);
  int mb = wgid % 48;
  int ks = wgid / 48;
  int w = threadIdx.x >> 6;
  int l = threadIdx.x & 63;
  int lr = l & 15;
  int lg = l >> 4;
  int row0 = mb * 128 + w * 64;
  int k0 = ks * KC;

  f32x4 acc[4][8];
#pragma unroll
  for (int rb = 0; rb < 4; rb++)
#pragma unroll
    for (int n = 0; n < 8; n++) acc[rb][n] = (f32x4){0.f, 0.f, 0.f, 0.f};

  const unsigned short* Ab = S + (size_t)(row0 + lr) * NN + k0 + lg * 8;
  const unsigned short* Bb = XT + (size_t)lr * NN + k0 + lg * 8;

#pragma unroll 4
  for (int kk = 0; kk < KC; kk += 32) {
    short8_t a0 = *(const short8_t*)(Ab + kk);
    short8_t a1 = *(const short8_t*)(Ab + (size_t)16 * NN + kk);
    short8_t a2 = *(const short8_t*)(Ab + (size_t)32 * NN + kk);
    short8_t a3 = *(const short8_t*)(Ab + (size_t)48 * NN + kk);
#pragma unroll
    for (int n = 0; n < 8; n++) {
      short8_t b = *(const short8_t*)(Bb + (size_t)n * 16 * NN + kk);
      acc[0][n] = __builtin_amdgcn_mfma_f32_16x16x32_bf16(a0, b, acc[0][n], 0, 0, 0);
      acc[1][n] = __builtin_amdgcn_mfma_f32_16x16x32_bf16(a1, b, acc[1][n], 0, 0, 0);
      acc[2][n] = __builtin_amdgcn_mfma_f32_16x16x32_bf16(a2, b, acc[2][n], 0, 0, 0);
      acc[3][n] = __builtin_amdgcn_mfma_f32_16x16x32_bf16(a3, b, acc[3][n], 0, 0, 0);
    }
  }

  // C/D layout: col = lane&15, row-in-16 = lg*4 + r
  float* pbase = partial + (size_t)ks * NN * F1;
#pragma unroll
  for (int rb = 0; rb < 4; rb++) {
    int rowo = row0 + rb * 16 + lg * 4;
#pragma unroll
    for (int n = 0; n < 8; n++) {
#pragma unroll
      for (int r = 0; r < 4; r++) {
        pbase[(size_t)(rowo + r) * F1 + n * 16 + lr] = acc[rb][n][r];
      }
    }
  }
}

// ---------------------------------------------------------------- finalize
__global__ __launch_bounds__(256) void finalize_kernel(
    const float4* __restrict__ partial, const float4* __restrict__ prevprev,
    float4* __restrict__ TxOut, unsigned short* __restrict__ XTout, int dsub) {
  const int TOT = NN * F1 / 4;
  int idx = blockIdx.x * 256 + threadIdx.x;
  float4 g = make_float4(0.f, 0.f, 0.f, 0.f);
#pragma unroll
  for (int s = 0; s < KSPLIT; s++) {
    float4 p = partial[(size_t)s * TOT + idx];
    g.x += p.x; g.y += p.y; g.z += p.z; g.w += p.w;
  }
  if (dsub) {
    float4 q = prevprev[idx];
    g.x = 2.f * g.x - q.x; g.y = 2.f * g.y - q.y;
    g.z = 2.f * g.z - q.z; g.w = 2.f * g.w - q.w;
  }
  TxOut[idx] = g;
  int f = idx << 2;
  int row = f >> 7;
  int col = f & 127;
  size_t b = (size_t)col * NN + row;
  XTout[b] = f2bf(g.x);
  XTout[b + NN] = f2bf(g.y);
  XTout[b + 2 * (size_t)NN] = f2bf(g.z);
  XTout[b + 3 * (size_t)NN] = f2bf(g.w);
}

// ---------------------------------------------------------------- epilogue
__global__ __launch_bounds__(256) void out_kernel(
    const float* __restrict__ Tx, const float* __restrict__ Wcat,
    const float* __restrict__ b3, const float* __restrict__ b6,
    const float* __restrict__ b9,
    const float* __restrict__ Wl, const float* __restrict__ bl,
    float* __restrict__ x_out, float* __restrict__ last_out) {
  __shared__ float WS[128 * 48];
  __shared__ float TxS[32][129];
  __shared__ float lo[32][48];
  __shared__ float lg[32][16];
  __shared__ float le[32][16];
  __shared__ float WlS[48 * 16];
  __shared__ float blS[16];
  int t = threadIdx.x;
  int row0 = blockIdx.x * 32;
  int rg = t >> 4;
  int cg = t & 15;
  float acc[2][3] = {{0.f, 0.f, 0.f}, {0.f, 0.f, 0.f}};
  for (int i = t; i < 768; i += 256) WlS[i] = Wl[i];
  if (t < 16) blS[t] = bl[t];
  for (int k = 0; k < 9; k++) {
    for (int i = t; i < 6144; i += 256) WS[i] = Wcat[k * 6144 + i];
    for (int i = t; i < 4096; i += 256) {
      int r = i >> 7, j = i & 127;
      TxS[r][j] = Tx[((size_t)k * NN + row0 + r) * F1 + j];
    }
    __syncthreads();
#pragma unroll 4
    for (int j = 0; j < 128; j++) {
      float t0 = TxS[2 * rg][j], t1 = TxS[2 * rg + 1][j];
      const float* wp = &WS[j * 48 + 3 * cg];
      float w0 = wp[0], w1 = wp[1], w2 = wp[2];
      acc[0][0] += t0 * w0; acc[0][1] += t0 * w1; acc[0][2] += t0 * w2;
      acc[1][0] += t1 * w0; acc[1][1] += t1 * w1; acc[1][2] += t1 * w2;
    }
    __syncthreads();
  }
#pragma unroll
  for (int rr = 0; rr < 2; rr++) {
    int r = 2 * rg + rr;
#pragma unroll
    for (int cc = 0; cc < 3; cc++) {
      int c = 3 * cg + cc;
      float bias = c < 16 ? b3[c] : (c < 32 ? b6[c - 16] : b9[c - 32]);
      float v = acc[rr][cc] + bias;
      lo[r][c] = v;
      last_out[(size_t)(row0 + r) * 48 + c] = v;
    }
  }
  __syncthreads();
#pragma unroll
  for (int s = 0; s < 2; s++) {
    int idx = t + 256 * s;
    int r = idx >> 4, c = idx & 15;
    float lgt = blS[c];
#pragma unroll 8
    for (int j = 0; j < 48; j++) lgt += lo[r][j] * WlS[j * 16 + c];
    lg[r][c] = lgt;
  }
  __syncthreads();
#pragma unroll
  for (int s = 0; s < 2; s++) {
    int idx = t + 256 * s;
    int r = idx >> 4, c = idx & 15;
    float mx = lg[r][0];
#pragma unroll
    for (int j = 1; j < 16; j++) mx = fmaxf(mx, lg[r][j]);
    le[r][c] = __expf(lg[r][c] - mx);
  }
  __syncthreads();
#pragma unroll
  for (int s = 0; s < 2; s++) {
    int idx = t + 256 * s;
    int r = idx >> 4, c = idx & 15;
    float sum = 0.f;
#pragma unroll
    for (int j = 0; j < 16; j++) sum += le[r][j];
    x_out[(size_t)(row0 + r) * 16 + c] = le[r][c] / sum;
  }
}

// ---------------------------------------------------------------- misc copies + Wcat build
__global__ __launch_bounds__(256) void copy_kernel(
    const int* __restrict__ tr, const int* __restrict__ val,
    const float* __restrict__ x0, float* __restrict__ tr_out,
    float* __restrict__ val_out, float* __restrict__ x0_out,
    const float* __restrict__ W3, const float* __restrict__ W6,
    const float* __restrict__ W9, float* __restrict__ Wcat) {
  int i = blockIdx.x * 256 + threadIdx.x;
  if (i < 4000) tr_out[i] = (float)tr[i];
  if (i < 1000) val_out[i] = (float)val[i];
  if (i < NN * 64) x0_out[i] = x0[i];
  if (i < 9 * 128 * 48) {
    int c = i % 48;
    int j = (i / 48) % 128;
    int k = i / (48 * 128);
    float v = 0.f;
    if (c < 16) {
      if (k < 3) v = W3[(k * 128 + j) * 16 + c];
    } else if (c < 32) {
      if (k < 6) v = W6[(k * 128 + j) * 16 + (c - 16)];
    } else {
      v = W9[(k * 128 + j) * 16 + (c - 32)];
    }
    Wcat[i] = v;
  }
}

extern "C" void kernel_launch(void* const* d_in, const int* in_sizes, int n_in,
                              void* d_out, int out_size, void* d_ws, size_t ws_size,
                              hipStream_t stream) {
  const float* x5 = (const float*)d_in[0];
  const float* x0 = (const float*)d_in[1];
  const int* tr = (const int*)d_in[2];
  const int* val = (const int*)d_in[3];
  const float* W_gat = (const float*)d_in[4];
  const float* b_gat = (const float*)d_in[5];
  const float* W_lin = (const float*)d_in[6];
  const float* b_lin = (const float*)d_in[7];
  const float* W3 = (const float*)d_in[8];
  const float* b3 = (const float*)d_in[9];
  const float* W6 = (const float*)d_in[10];
  const float* b6 = (const float*)d_in[11];
  const float* W9 = (const float*)d_in[12];
  const float* b9 = (const float*)d_in[13];
  const float* Wl = (const float*)d_in[14];
  const float* bl = (const float*)d_in[15];

  float* out = (float*)d_out;
  float* x_out = out;
  float* tr_out = x_out + (size_t)NN * 16;
  float* val_out = tr_out + 4000;
  float* P = val_out + 1000;
  float* last_out = P + (size_t)NN * NN;
  float* x0_out = last_out + (size_t)NN * 48;

  char* w = (char*)d_ws;
  unsigned short* Sb = (unsigned short*)w;  w += (size_t)NN * NN * 2;
  float* Tx = (float*)w;                    w += (size_t)9 * NN * F1 * 4;
  float* partial = (float*)w;               w += (size_t)KSPLIT * NN * F1 * 4;
  unsigned short* XTa = (unsigned short*)w; w += (size_t)NN * F1 * 2;
  unsigned short* XTb = (unsigned short*)w; w += (size_t)NN * F1 * 2;
  float* hT = (float*)w;                    w += (size_t)6 * NN * 4;
  float* sq = (float*)w;                    w += (size_t)NN * 4;
  float* dinv = (float*)w;                  w += (size_t)NN * 4;
  float* Wcat = (float*)w;                  w += (size_t)9 * 128 * 48 * 4;

  prep_kernel<<<NN, 128, 0, stream>>>(x5, x0, W_gat, b_gat, W_lin, b_lin, hT, sq,
                                      Tx, XTa);
  prob_kernel<<<NN, 256, 0, stream>>>(hT, sq, P, dinv);
  smat_kernel<<<NN, 256, 0, stream>>>(hT, sq, dinv, Sb);
  copy_kernel<<<1536, 256, 0, stream>>>(tr, val, x0, tr_out, val_out, x0_out,
                                        W3, W6, W9, Wcat);

  unsigned short* xin = XTa;
  unsigned short* xout = XTb;
  for (int k = 1; k <= 8; k++) {
    gemm_kernel<<<1152, 128, 0, stream>>>(Sb, xin, partial);
    const float4* pp = (const float4*)(Tx + (size_t)(k >= 2 ? k - 2 : 0) * NN * F1);
    finalize_kernel<<<768, 256, 0, stream>>>((const float4*)partial, pp,
                                             (float4*)(Tx + (size_t)k * NN * F1),
                                             xout, k >= 2 ? 1 : 0);
    unsigned short* tmp = xin; xin = xout; xout = tmp;
  }

  out_kernel<<<192, 256, 0, stream>>>(Tx, Wcat, b3, b6, b9, Wl, bl, x_out,
                                      last_out);
}

// Round 5
// 550.718 us; speedup vs baseline: 2.0397x; 1.1163x over previous
//
#include <hip/hip_runtime.h>

#define NN 6144
#define F1 128
#define KSPLIT 8
#define KC 768

typedef __attribute__((ext_vector_type(8))) short short8_t;
typedef __attribute__((ext_vector_type(4))) float f32x4;

__device__ __forceinline__ unsigned short f2bf(float f) {
  unsigned int u = __float_as_uint(f);
  unsigned int r = (u + 0x7fffu + ((u >> 16) & 1u)) >> 16;
  return (unsigned short)r;
}

// ---------------------------------------------------------------- prep
__global__ __launch_bounds__(128) void prep_kernel(
    const float* __restrict__ x5, const float* __restrict__ x0,
    const float* __restrict__ W_gat, const float* __restrict__ b_gat,
    const float* __restrict__ W_lin, const float* __restrict__ b_lin,
    float* __restrict__ hT, float* __restrict__ sq,
    float* __restrict__ Tx0, unsigned short* __restrict__ XT0) {
  int i = blockIdx.x;
  int t = threadIdx.x;
  __shared__ float xs[64];
  __shared__ float x5s[3];
  __shared__ float hs[6];
  if (t < 3) x5s[t] = x5[i * 3 + t];
  if (t < 64) xs[t] = x0[(size_t)i * 64 + t];
  __syncthreads();
  if (t < 6) {
    float a = b_gat[t];
#pragma unroll
    for (int k = 0; k < 3; k++) a += x5s[k] * W_gat[k * 6 + t];
    a = fmaxf(a, 0.f);
    hs[t] = a;
    hT[(size_t)t * NN + i] = a;
  }
  __syncthreads();
  if (t == 0) {
    float s = 0.f;
#pragma unroll
    for (int k = 0; k < 6; k++) s += hs[k] * hs[k];
    sq[i] = s;
  }
  float a = b_lin[t];
#pragma unroll 16
  for (int k = 0; k < 64; k++) a += xs[k] * W_lin[k * 128 + t];
  a = fmaxf(a, 0.f);
  Tx0[(size_t)i * F1 + t] = a;
  XT0[(size_t)t * NN + i] = f2bf(a);
}

// ---------------------------------------------------------------- prob
__global__ __launch_bounds__(256) void prob_kernel(
    const float* __restrict__ hT, const float* __restrict__ sq,
    float* __restrict__ P, float* __restrict__ dinv) {
  int i = blockIdx.x;
  int t = threadIdx.x;
  float h0 = hT[i], h1 = hT[NN + i], h2 = hT[2 * NN + i];
  float h3 = hT[3 * NN + i], h4 = hT[4 * NN + i], h5 = hT[5 * NN + i];
  float si = sq[i];
  float acc = 0.f;
  float* Pr = P + (size_t)i * NN;
  for (int j = t; j < NN; j += 256) {
    float dot = h0 * hT[j] + h1 * hT[NN + j] + h2 * hT[2 * NN + j] +
                h3 * hT[3 * NN + j] + h4 * hT[4 * NN + j] + h5 * hT[5 * NN + j];
    float d = si + sq[j] - 2.f * dot;
    float p = __expf(-0.5f * d);
    Pr[j] = p;
    if (j != i) acc += p;
  }
  __shared__ float red[256];
  red[t] = acc;
  __syncthreads();
  for (int s = 128; s > 0; s >>= 1) {
    if (t < s) red[t] += red[t + s];
    __syncthreads();
  }
  if (t == 0) {
    float deg = red[0];
    dinv[i] = deg > 0.f ? rsqrtf(deg) : 0.f;
  }
}

// ---------------------------------------------------------------- smat
__global__ __launch_bounds__(256) void smat_kernel(
    const float* __restrict__ hT, const float* __restrict__ sq,
    const float* __restrict__ dinv, unsigned short* __restrict__ Sb) {
  int i = blockIdx.x;
  int t = threadIdx.x;
  float h0 = hT[i], h1 = hT[NN + i], h2 = hT[2 * NN + i];
  float h3 = hT[3 * NN + i], h4 = hT[4 * NN + i], h5 = hT[5 * NN + i];
  float si = sq[i];
  float di = dinv[i];
  unsigned short* Sr = Sb + (size_t)i * NN;
  for (int j = t; j < NN; j += 256) {
    float dot = h0 * hT[j] + h1 * hT[NN + j] + h2 * hT[2 * NN + j] +
                h3 * hT[3 * NN + j] + h4 * hT[4 * NN + j] + h5 * hT[5 * NN + j];
    float d = si + sq[j] - 2.f * dot;
    float p = __expf(-0.5f * d);
    float s = (j == i) ? 0.f : -(di * p * dinv[j]);
    Sr[j] = f2bf(s);
  }
}

// ---------------------------------------------------------------- gemm (split-K partials)
// grid 384 = (48 mb x 8 ks), block 128 (2 waves, both in M); wave = 64 rows x
// 128 cols, KC=768. Traffic/step: A 75.5 + B 75 + partial 2x25.2 = 201 MB.
__global__ __launch_bounds__(128) void gemm_kernel(
    const unsigned short* __restrict__ S, const unsigned short* __restrict__ XT,
    float* __restrict__ partial) {
  // bijective XCD swizzle: 384 = 8 XCDs x 48; each XCD gets all mb of one ks
  // -> shared 196 KB B-chunk is L2-resident per XCD.
  int orig = blockIdx.x;
  int wgid = (orig & 7) * 48 + (orig >> 3);
  int mb = wgid % 48;
  int ks = wgid / 48;
  int w = threadIdx.x >> 6;
  int l = threadIdx.x & 63;
  int lr = l & 15;
  int lg = l >> 4;
  int row0 = mb * 128 + w * 64;
  int k0 = ks * KC;

  f32x4 acc[4][8];
#pragma unroll
  for (int rb = 0; rb < 4; rb++)
#pragma unroll
    for (int n = 0; n < 8; n++) acc[rb][n] = (f32x4){0.f, 0.f, 0.f, 0.f};

  const unsigned short* Ab = S + (size_t)(row0 + lr) * NN + k0 + lg * 8;
  const unsigned short* Bb = XT + (size_t)lr * NN + k0 + lg * 8;

#pragma unroll 3
  for (int kk = 0; kk < KC; kk += 32) {
    short8_t a0 = *(const short8_t*)(Ab + kk);
    short8_t a1 = *(const short8_t*)(Ab + (size_t)16 * NN + kk);
    short8_t a2 = *(const short8_t*)(Ab + (size_t)32 * NN + kk);
    short8_t a3 = *(const short8_t*)(Ab + (size_t)48 * NN + kk);
#pragma unroll
    for (int n = 0; n < 8; n++) {
      short8_t b = *(const short8_t*)(Bb + (size_t)n * 16 * NN + kk);
      acc[0][n] = __builtin_amdgcn_mfma_f32_16x16x32_bf16(a0, b, acc[0][n], 0, 0, 0);
      acc[1][n] = __builtin_amdgcn_mfma_f32_16x16x32_bf16(a1, b, acc[1][n], 0, 0, 0);
      acc[2][n] = __builtin_amdgcn_mfma_f32_16x16x32_bf16(a2, b, acc[2][n], 0, 0, 0);
      acc[3][n] = __builtin_amdgcn_mfma_f32_16x16x32_bf16(a3, b, acc[3][n], 0, 0, 0);
    }
  }

  // C/D layout: col = lane&15, row-in-16 = lg*4 + r
  float* pbase = partial + (size_t)ks * NN * F1;
#pragma unroll
  for (int rb = 0; rb < 4; rb++) {
    int rowo = row0 + rb * 16 + lg * 4;
#pragma unroll
    for (int n = 0; n < 8; n++) {
#pragma unroll
      for (int r = 0; r < 4; r++) {
        pbase[(size_t)(rowo + r) * F1 + n * 16 + lr] = acc[rb][n][r];
      }
    }
  }
}

// ---------------------------------------------------------------- finalize
__global__ __launch_bounds__(256) void finalize_kernel(
    const float4* __restrict__ partial, const float4* __restrict__ prevprev,
    float4* __restrict__ TxOut, unsigned short* __restrict__ XTout, int dsub) {
  const int TOT = NN * F1 / 4;
  int idx = blockIdx.x * 256 + threadIdx.x;
  float4 g = make_float4(0.f, 0.f, 0.f, 0.f);
#pragma unroll
  for (int s = 0; s < KSPLIT; s++) {
    float4 p = partial[(size_t)s * TOT + idx];
    g.x += p.x; g.y += p.y; g.z += p.z; g.w += p.w;
  }
  if (dsub) {
    float4 q = prevprev[idx];
    g.x = 2.f * g.x - q.x; g.y = 2.f * g.y - q.y;
    g.z = 2.f * g.z - q.z; g.w = 2.f * g.w - q.w;
  }
  TxOut[idx] = g;
  int f = idx << 2;
  int row = f >> 7;
  int col = f & 127;
  size_t b = (size_t)col * NN + row;
  XTout[b] = f2bf(g.x);
  XTout[b + NN] = f2bf(g.y);
  XTout[b + 2 * (size_t)NN] = f2bf(g.z);
  XTout[b + 3 * (size_t)NN] = f2bf(g.w);
}

// ---------------------------------------------------------------- epilogue
__global__ __launch_bounds__(256) void out_kernel(
    const float* __restrict__ Tx, const float* __restrict__ Wcat,
    const float* __restrict__ b3, const float* __restrict__ b6,
    const float* __restrict__ b9,
    const float* __restrict__ Wl, const float* __restrict__ bl,
    float* __restrict__ x_out, float* __restrict__ last_out) {
  __shared__ float WS[128 * 48];
  __shared__ float TxS[32][129];
  __shared__ float lo[32][48];
  __shared__ float lg[32][16];
  __shared__ float le[32][16];
  __shared__ float WlS[48 * 16];
  __shared__ float blS[16];
  int t = threadIdx.x;
  int row0 = blockIdx.x * 32;
  int rg = t >> 4;
  int cg = t & 15;
  float acc[2][3] = {{0.f, 0.f, 0.f}, {0.f, 0.f, 0.f}};
  for (int i = t; i < 768; i += 256) WlS[i] = Wl[i];
  if (t < 16) blS[t] = bl[t];
  for (int k = 0; k < 9; k++) {
    for (int i = t; i < 6144; i += 256) WS[i] = Wcat[k * 6144 + i];
    for (int i = t; i < 4096; i += 256) {
      int r = i >> 7, j = i & 127;
      TxS[r][j] = Tx[((size_t)k * NN + row0 + r) * F1 + j];
    }
    __syncthreads();
#pragma unroll 4
    for (int j = 0; j < 128; j++) {
      float t0 = TxS[2 * rg][j], t1 = TxS[2 * rg + 1][j];
      const float* wp = &WS[j * 48 + 3 * cg];
      float w0 = wp[0], w1 = wp[1], w2 = wp[2];
      acc[0][0] += t0 * w0; acc[0][1] += t0 * w1; acc[0][2] += t0 * w2;
      acc[1][0] += t1 * w0; acc[1][1] += t1 * w1; acc[1][2] += t1 * w2;
    }
    __syncthreads();
  }
#pragma unroll
  for (int rr = 0; rr < 2; rr++) {
    int r = 2 * rg + rr;
#pragma unroll
    for (int cc = 0; cc < 3; cc++) {
      int c = 3 * cg + cc;
      float bias = c < 16 ? b3[c] : (c < 32 ? b6[c - 16] : b9[c - 32]);
      float v = acc[rr][cc] + bias;
      lo[r][c] = v;
      last_out[(size_t)(row0 + r) * 48 + c] = v;
    }
  }
  __syncthreads();
#pragma unroll
  for (int s = 0; s < 2; s++) {
    int idx = t + 256 * s;
    int r = idx >> 4, c = idx & 15;
    float lgt = blS[c];
#pragma unroll 8
    for (int j = 0; j < 48; j++) lgt += lo[r][j] * WlS[j * 16 + c];
    lg[r][c] = lgt;
  }
  __syncthreads();
#pragma unroll
  for (int s = 0; s < 2; s++) {
    int idx = t + 256 * s;
    int r = idx >> 4, c = idx & 15;
    float mx = lg[r][0];
#pragma unroll
    for (int j = 1; j < 16; j++) mx = fmaxf(mx, lg[r][j]);
    le[r][c] = __expf(lg[r][c] - mx);
  }
  __syncthreads();
#pragma unroll
  for (int s = 0; s < 2; s++) {
    int idx = t + 256 * s;
    int r = idx >> 4, c = idx & 15;
    float sum = 0.f;
#pragma unroll
    for (int j = 0; j < 16; j++) sum += le[r][j];
    x_out[(size_t)(row0 + r) * 16 + c] = le[r][c] / sum;
  }
}

// ---------------------------------------------------------------- misc copies + Wcat build
__global__ __launch_bounds__(256) void copy_kernel(
    const int* __restrict__ tr, const int* __restrict__ val,
    const float* __restrict__ x0, float* __restrict__ tr_out,
    float* __restrict__ val_out, float* __restrict__ x0_out,
    const float* __restrict__ W3, const float* __restrict__ W6,
    const float* __restrict__ W9, float* __restrict__ Wcat) {
  int i = blockIdx.x * 256 + threadIdx.x;
  if (i < 4000) tr_out[i] = (float)tr[i];
  if (i < 1000) val_out[i] = (float)val[i];
  if (i < NN * 64) x0_out[i] = x0[i];
  if (i < 9 * 128 * 48) {
    int c = i % 48;
    int j = (i / 48) % 128;
    int k = i / (48 * 128);
    float v = 0.f;
    if (c < 16) {
      if (k < 3) v = W3[(k * 128 + j) * 16 + c];
    } else if (c < 32) {
      if (k < 6) v = W6[(k * 128 + j) * 16 + (c - 16)];
    } else {
      v = W9[(k * 128 + j) * 16 + (c - 32)];
    }
    Wcat[i] = v;
  }
}

extern "C" void kernel_launch(void* const* d_in, const int* in_sizes, int n_in,
                              void* d_out, int out_size, void* d_ws, size_t ws_size,
                              hipStream_t stream) {
  const float* x5 = (const float*)d_in[0];
  const float* x0 = (const float*)d_in[1];
  const int* tr = (const int*)d_in[2];
  const int* val = (const int*)d_in[3];
  const float* W_gat = (const float*)d_in[4];
  const float* b_gat = (const float*)d_in[5];
  const float* W_lin = (const float*)d_in[6];
  const float* b_lin = (const float*)d_in[7];
  const float* W3 = (const float*)d_in[8];
  const float* b3 = (const float*)d_in[9];
  const float* W6 = (const float*)d_in[10];
  const float* b6 = (const float*)d_in[11];
  const float* W9 = (const float*)d_in[12];
  const float* b9 = (const float*)d_in[13];
  const float* Wl = (const float*)d_in[14];
  const float* bl = (const float*)d_in[15];

  float* out = (float*)d_out;
  float* x_out = out;
  float* tr_out = x_out + (size_t)NN * 16;
  float* val_out = tr_out + 4000;
  float* P = val_out + 1000;
  float* last_out = P + (size_t)NN * NN;
  float* x0_out = last_out + (size_t)NN * 48;

  char* w = (char*)d_ws;
  unsigned short* Sb = (unsigned short*)w;  w += (size_t)NN * NN * 2;
  float* Tx = (float*)w;                    w += (size_t)9 * NN * F1 * 4;
  float* partial = (float*)w;               w += (size_t)KSPLIT * NN * F1 * 4;
  unsigned short* XTa = (unsigned short*)w; w += (size_t)NN * F1 * 2;
  unsigned short* XTb = (unsigned short*)w; w += (size_t)NN * F1 * 2;
  float* hT = (float*)w;                    w += (size_t)6 * NN * 4;
  float* sq = (float*)w;                    w += (size_t)NN * 4;
  float* dinv = (float*)w;                  w += (size_t)NN * 4;
  float* Wcat = (float*)w;                  w += (size_t)9 * 128 * 48 * 4;

  prep_kernel<<<NN, 128, 0, stream>>>(x5, x0, W_gat, b_gat, W_lin, b_lin, hT, sq,
                                      Tx, XTa);
  prob_kernel<<<NN, 256, 0, stream>>>(hT, sq, P, dinv);
  smat_kernel<<<NN, 256, 0, stream>>>(hT, sq, dinv, Sb);
  copy_kernel<<<1536, 256, 0, stream>>>(tr, val, x0, tr_out, val_out, x0_out,
                                        W3, W6, W9, Wcat);

  unsigned short* xin = XTa;
  unsigned short* xout = XTb;
  for (int k = 1; k <= 8; k++) {
    gemm_kernel<<<384, 128, 0, stream>>>(Sb, xin, partial);
    const float4* pp = (const float4*)(Tx + (size_t)(k >= 2 ? k - 2 : 0) * NN * F1);
    finalize_kernel<<<768, 256, 0, stream>>>((const float4*)partial, pp,
                                             (float4*)(Tx + (size_t)k * NN * F1),
                                             xout, k >= 2 ? 1 : 0);
    unsigned short* tmp = xin; xin = xout; xout = tmp;
  }

  out_kernel<<<192, 256, 0, stream>>>(Tx, Wcat, b3, b6, b9, Wl, bl, x_out,
                                      last_out);
}